// Round 3
// baseline (174.762 us; speedup 1.0000x reference)
//
#include <hip/hip_runtime.h>
#include <hip/hip_bf16.h>

#define B_DIM 64
#define I_DIM 16384
#define O_DIM 1024
#define K_BASIS 5
#define H_DIM 16
#define IK (I_DIM * K_BASIS)   // 81920

typedef __attribute__((ext_vector_type(8))) short short8;
typedef __attribute__((ext_vector_type(4))) float f32x4;

// ---------------------------------------------------------------------------
// Kernel 1: basis[b][i] = w2[i%5] . silu(x[b][i]*w1[i%5] + b1[i%5]) + b2[i%5]
// float4-packed params in LDS (1 ds_read_b128/h), rcp-based silu.
// ---------------------------------------------------------------------------
__global__ __launch_bounds__(256)
void basis_kernel(const float* __restrict__ x,
                  const float* __restrict__ w1,
                  const float* __restrict__ b1,
                  const float* __restrict__ w2,
                  const float* __restrict__ b2,
                  __hip_bfloat16* __restrict__ basis) {
    __shared__ float4 pk[K_BASIS][H_DIM + 1];   // {w1,b1,w2,0}, padded row
    __shared__ float pb2[K_BASIS];
    const int t = threadIdx.x;
    if (t < K_BASIS * H_DIM) {
        const int k = t / H_DIM, h = t % H_DIM;
        pk[k][h] = float4{w1[t], b1[t], w2[t], 0.f};
        if (t < K_BASIS) pb2[t] = b2[t];
    }
    __syncthreads();

    const int gid = blockIdx.x * 256 + t;        // 0 .. 131071
    const int i8 = gid % (I_DIM / 8);
    const int b  = gid / (I_DIM / 8);
    const int i0 = i8 * 8;

    const float4* xp = reinterpret_cast<const float4*>(x + (size_t)b * I_DIM + i0);
    float4 xa = xp[0];
    float4 xb = xp[1];
    float xs[8] = {xa.x, xa.y, xa.z, xa.w, xb.x, xb.y, xb.z, xb.w};

    __hip_bfloat16 res[8];
#pragma unroll
    for (int j = 0; j < 8; ++j) {
        const int idx = (i0 + j) % K_BASIS;
        const float xv = xs[j];
        float acc = 0.f;
#pragma unroll
        for (int h = 0; h < H_DIM; ++h) {
            const float4 p = pk[idx][h];
            float a = fmaf(xv, p.x, p.y);
            float s = a * __builtin_amdgcn_rcpf(1.f + __expf(-a));   // silu
            acc = fmaf(s, p.z, acc);
        }
        res[j] = __float2bfloat16(acc + pb2[idx]);
    }
    *reinterpret_cast<short8*>(basis + (size_t)b * I_DIM + i0) =
        *reinterpret_cast<short8*>(res);
}

// ---------------------------------------------------------------------------
// Kernel 2: out[64,1024] = basis[64,16384] @ Wsum[16384,1024]
// Block: 16 o-rows x 512 i (4 chunks of 128 i). W streamed in 2560B-contiguous
// runs per row with flat-coalesced float4 loads -> linear LDS. Fold 5->1
// during LDS->reg read. Waves split the 128-i chunk as 4 k-slices of 32
// (atomicAdd epilogue sums all k-partials). A-frags direct from L2 basis.
// ---------------------------------------------------------------------------
#define NT 16          // o-rows per block
#define CI 128         // i per chunk
#define NCHUNK 4       // i per block = 512
#define CHUNK_F4 (NT * CI * K_BASIS / 4)   // 2560 float4 slots per chunk

__global__ __launch_bounds__(256, 4)
void kan_gemm(const float* __restrict__ W,
              const __hip_bfloat16* __restrict__ basis,
              float* __restrict__ out) {
    __shared__ float Ws[NT * CI * K_BASIS];      // [16][640] f32, 40 KiB, linear

    const int t    = threadIdx.x;
    const int lane = t & 63;
    const int wv   = t >> 6;                     // k-slice within chunk
    const int o0   = blockIdx.x * NT;            // 64 o-tiles
    const int i00  = blockIdx.y * (CI * NCHUNK); // 32 k-splits

    const int col  = lane & 15;
    const int kgrp = lane >> 4;

    // staging geometry (flat, coalesced): slot s = t + 256r -> row=s/160, c4=s%160
    int gidx[10];                                // f32 index of slot base in W row-space
#pragma unroll
    for (int r = 0; r < 10; ++r) {
        const int s   = t + r * 256;
        const int row = s / 160;
        const int c4  = s - row * 160;
        gidx[r] = (o0 + row) * IK + c4 * 4;      // + ikb at issue time
    }

    float4 wr[10];
    auto issue = [&](int c) {
        const int ikb = (i00 + c * CI) * K_BASIS;
#pragma unroll
        for (int r = 0; r < 10; ++r)
            wr[r] = *reinterpret_cast<const float4*>(W + (size_t)gidx[r] + ikb);
    };
    auto commit = [&]() {
#pragma unroll
        for (int r = 0; r < 10; ++r)
            *reinterpret_cast<float4*>(&Ws[(t + r * 256) * 4]) = wr[r];
    };

    f32x4 acc[4] = {f32x4{0,0,0,0}, f32x4{0,0,0,0}, f32x4{0,0,0,0}, f32x4{0,0,0,0}};
    const int fold_base = col * (CI * K_BASIS) + wv * 160 + kgrp * 40;

    // prologue: stage chunk 0
    issue(0);
    commit();
    __syncthreads();

    for (int c = 0; c < NCHUNK; ++c) {
        const int i0c = i00 + c * CI + wv * 32 + kgrp * 8;

        // A-fragments first (oldest vmem -> counted wait leaves W loads in flight)
        short8 af[4];
#pragma unroll
        for (int m = 0; m < 4; ++m)
            af[m] = *reinterpret_cast<const short8*>(
                basis + (size_t)(m * 16 + col) * I_DIM + i0c);
        __builtin_amdgcn_sched_barrier(0);

        if (c + 1 < NCHUNK) issue(c + 1);        // next-chunk W loads fly over compute
        __builtin_amdgcn_sched_barrier(0);

        // fold-read: 40 consecutive f32 -> 8 Wsum bf16 (this wave's 32-i k-slice)
        float ws[8] = {0.f, 0.f, 0.f, 0.f, 0.f, 0.f, 0.f, 0.f};
#pragma unroll
        for (int q = 0; q < 10; ++q) {
            const float4 v = *reinterpret_cast<const float4*>(&Ws[fold_base + q * 4]);
            ws[(4 * q + 0) / 5] += v.x;
            ws[(4 * q + 1) / 5] += v.y;
            ws[(4 * q + 2) / 5] += v.z;
            ws[(4 * q + 3) / 5] += v.w;
        }
        __hip_bfloat16 wsb[8];
#pragma unroll
        for (int j = 0; j < 8; ++j) wsb[j] = __float2bfloat16(ws[j]);
        const short8 bf = *reinterpret_cast<short8*>(wsb);

#pragma unroll
        for (int m = 0; m < 4; ++m)
            acc[m] = __builtin_amdgcn_mfma_f32_16x16x32_bf16(af[m], bf, acc[m], 0, 0, 0);

        if (c + 1 < NCHUNK) {
            __builtin_amdgcn_sched_barrier(0);
            __builtin_amdgcn_s_barrier();        // raw: W loads stay in flight
            commit();                            // vmcnt-waits wr, writes LDS
            __syncthreads();                     // publish chunk c+1
        }
    }

    // epilogue: atomic accumulate 64x16 tile (waves are k-partials of same tile)
#pragma unroll
    for (int m = 0; m < 4; ++m) {
#pragma unroll
        for (int j = 0; j < 4; ++j) {
            const int brow = m * 16 + kgrp * 4 + j;
            atomicAdd(&out[(size_t)brow * O_DIM + o0 + col], acc[m][j]);
        }
    }
}

// ---------------------------------------------------------------------------
extern "C" void kernel_launch(void* const* d_in, const int* in_sizes, int n_in,
                              void* d_out, int out_size, void* d_ws, size_t ws_size,
                              hipStream_t stream) {
    const float* x  = (const float*)d_in[0];
    const float* w1 = (const float*)d_in[1];
    const float* b1 = (const float*)d_in[2];
    const float* w2 = (const float*)d_in[3];
    const float* b2 = (const float*)d_in[4];
    const float* W  = (const float*)d_in[5];
    float* out = (float*)d_out;
    __hip_bfloat16* basis = (__hip_bfloat16*)d_ws;   // 64*16384*2 = 2 MiB

    hipMemsetAsync(d_out, 0, (size_t)out_size * sizeof(float), stream);

    basis_kernel<<<dim3((B_DIM * I_DIM / 8) / 256), dim3(256), 0, stream>>>(
        x, w1, b1, w2, b2, basis);

    dim3 grid(O_DIM / NT, I_DIM / (CI * NCHUNK));   // (64, 32)
    kan_gemm<<<grid, dim3(256), 0, stream>>>(W, basis, out);
}

// Round 5
// 92.006 us; speedup vs baseline: 1.8995x; 1.8995x over previous
//
#include <hip/hip_runtime.h>
#include <hip/hip_bf16.h>

#define B_DIM 64
#define I_DIM 16384
#define O_DIM 1024
#define K_BASIS 5
#define H_DIM 16
#define IK (I_DIM * K_BASIS)   // 81920

typedef __attribute__((ext_vector_type(8))) short short8;
typedef __attribute__((ext_vector_type(4))) float f32x4;

// ---------------------------------------------------------------------------
// Kernel 1: basis[b][i] = w2[i%5] . silu(x[b][i]*w1[i%5] + b1[i%5]) + b2[i%5]
// ---------------------------------------------------------------------------
__global__ __launch_bounds__(256)
void basis_kernel(const float* __restrict__ x,
                  const float* __restrict__ w1,
                  const float* __restrict__ b1,
                  const float* __restrict__ w2,
                  const float* __restrict__ b2,
                  __hip_bfloat16* __restrict__ basis) {
    __shared__ float4 pk[K_BASIS][H_DIM + 1];   // {w1,b1,w2,0}
    __shared__ float pb2[K_BASIS];
    const int t = threadIdx.x;
    if (t < K_BASIS * H_DIM) {
        const int k = t / H_DIM, h = t % H_DIM;
        pk[k][h] = float4{w1[t], b1[t], w2[t], 0.f};
        if (t < K_BASIS) pb2[t] = b2[t];
    }
    __syncthreads();

    const int gid = blockIdx.x * 256 + t;
    const int i8 = gid % (I_DIM / 8);
    const int b  = gid / (I_DIM / 8);
    const int i0 = i8 * 8;

    const float4* xp = reinterpret_cast<const float4*>(x + (size_t)b * I_DIM + i0);
    float4 xa = xp[0];
    float4 xb = xp[1];
    float xs[8] = {xa.x, xa.y, xa.z, xa.w, xb.x, xb.y, xb.z, xb.w};

    __hip_bfloat16 res[8];
#pragma unroll
    for (int j = 0; j < 8; ++j) {
        const int idx = (i0 + j) % K_BASIS;
        const float xv = xs[j];
        float acc = 0.f;
#pragma unroll
        for (int h = 0; h < H_DIM; ++h) {
            const float4 p = pk[idx][h];
            float a = fmaf(xv, p.x, p.y);
            float s = a * __builtin_amdgcn_rcpf(1.f + __expf(-a));   // silu
            acc = fmaf(s, p.z, acc);
        }
        res[j] = __float2bfloat16(acc + pb2[idx]);
    }
    *reinterpret_cast<short8*>(basis + (size_t)b * I_DIM + i0) =
        *reinterpret_cast<short8*>(res);
}

// ---------------------------------------------------------------------------
// Kernel 2: out[64,1024] = basis[64,16384] @ Wsum[16384,1024]
// NT=16 o-rows/WG, CI=128 i/chunk, 16 chunks/WG (40 KB contiguous per W row).
// Register-fold staging (40 consecutive f32 -> 8 bf16 per thread), double
// LDS buffer, ONE race-proof raw barrier per chunk, vmcnt never drained.
// Waves = 4 k-slices; LDS cross-wave reduce; 1024 atomics/WG.
// ---------------------------------------------------------------------------
#define NT 16
#define CI 128
#define KSPLIT 8
#define NCHUNK (I_DIM / KSPLIT / CI)   // 16
#define LDBS 136                        // Bs row stride in bf16 (272 B -> 2-way max)

#define PUBLISH() do {                                                  \
        asm volatile("s_waitcnt lgkmcnt(0)" ::: "memory");              \
        __builtin_amdgcn_s_barrier();                                   \
        asm volatile("" ::: "memory");                                  \
    } while (0)

__global__ __launch_bounds__(256)
void kan_gemm(const float* __restrict__ W,
              const __hip_bfloat16* __restrict__ basis,
              float* __restrict__ out) {
    __shared__ float4 smem[1024];                       // 16 KiB
    __hip_bfloat16* Bs0 = reinterpret_cast<__hip_bfloat16*>(smem);  // [16][136]
    __hip_bfloat16* Bs1 = Bs0 + NT * LDBS;
    float* red = reinterpret_cast<float*>(smem);        // epilogue [4][1024]

    const int t    = threadIdx.x;
    const int lane = t & 63;
    const int wv   = t >> 6;          // k-slice 0..3
    const int col  = lane & 15;
    const int kgrp = lane >> 4;
    const int o0   = blockIdx.x * NT;
    const int i00  = blockIdx.y * (CI * NCHUNK);        // 2048-i band

    // staging geometry: thread = (o-row, 40-float segment)
    const int srow = t >> 4;          // 0..15
    const int sseg = t & 15;          // 0..15
    const float* wbase = W + (size_t)(o0 + srow) * IK + (size_t)i00 * K_BASIS
                           + sseg * 40;
    const __hip_bfloat16* abase = basis + i00 + wv * 32 + kgrp * 8;

    float4 ra[10], rb[10];
    short8 af[4];

#define ISSUE(R, c) do {                                                \
        const float4* p = reinterpret_cast<const float4*>(              \
            wbase + (size_t)(c) * (CI * K_BASIS));                      \
        _Pragma("unroll") for (int q = 0; q < 10; ++q) R[q] = p[q];     \
    } while (0)

#define COMMIT(BS, R) do {                                              \
        float ws[8] = {0.f,0.f,0.f,0.f,0.f,0.f,0.f,0.f};                \
        _Pragma("unroll") for (int q = 0; q < 10; ++q) {                \
            ws[(4*q+0)/5] += R[q].x;                                    \
            ws[(4*q+1)/5] += R[q].y;                                    \
            ws[(4*q+2)/5] += R[q].z;                                    \
            ws[(4*q+3)/5] += R[q].w;                                    \
        }                                                               \
        __hip_bfloat16 wb8[8];                                          \
        _Pragma("unroll") for (int u = 0; u < 8; ++u)                   \
            wb8[u] = __float2bfloat16(ws[u]);                           \
        *reinterpret_cast<short8*>(&BS[srow * LDBS + sseg * 8]) =       \
            *reinterpret_cast<short8*>(wb8);                            \
    } while (0)

#define AFLOAD(c) do {                                                  \
        _Pragma("unroll") for (int m = 0; m < 4; ++m)                   \
            af[m] = *reinterpret_cast<const short8*>(                   \
                abase + (size_t)(m * 16 + col) * I_DIM + (c) * CI);     \
    } while (0)

#define COMPUTE(BS) do {                                                \
        const short8 bfr = *reinterpret_cast<const short8*>(            \
            &BS[col * LDBS + wv * 32 + kgrp * 8]);                      \
        _Pragma("unroll") for (int m = 0; m < 4; ++m)                   \
            acc[m] = __builtin_amdgcn_mfma_f32_16x16x32_bf16(           \
                af[m], bfr, acc[m], 0, 0, 0);                           \
    } while (0)

    f32x4 acc[4] = {f32x4{0,0,0,0}, f32x4{0,0,0,0}, f32x4{0,0,0,0}, f32x4{0,0,0,0}};

    // prologue: chunks 0,1 in flight; publish chunk 0 in Bs0
    ISSUE(ra, 0);
    ISSUE(rb, 1);
    COMMIT(Bs0, ra);
    PUBLISH();

#pragma unroll
    for (int cc = 0; cc < NCHUNK; cc += 2) {
        // ---- even chunk cc (in Bs0) ----
        AFLOAD(cc);
        __builtin_amdgcn_sched_barrier(0);      // keep af older than next ISSUE
        if (cc + 2 < NCHUNK) ISSUE(ra, cc + 2);
        COMMIT(Bs1, rb);                        // chunk cc+1 -> Bs1 (counted vmcnt)
        COMPUTE(Bs0);
        PUBLISH();
        // ---- odd chunk cc+1 (in Bs1) ----
        AFLOAD(cc + 1);
        __builtin_amdgcn_sched_barrier(0);
        if (cc + 3 < NCHUNK) ISSUE(rb, cc + 3);
        if (cc + 2 < NCHUNK) COMMIT(Bs0, ra);   // chunk cc+2 -> Bs0
        COMPUTE(Bs1);
        if (cc + 2 < NCHUNK) PUBLISH();
    }
    PUBLISH();                                  // all LDS reads done before reuse

    // ---- epilogue: cross-wave reduce in LDS, then 4 atomics/thread ----
#pragma unroll
    for (int m = 0; m < 4; ++m)
#pragma unroll
        for (int j = 0; j < 4; ++j)
            red[wv * 1024 + (m * 16 + kgrp * 4 + j) * 16 + col] = acc[m][j];
    PUBLISH();

    const float4 v0 = *reinterpret_cast<const float4*>(&red[0 * 1024 + t * 4]);
    const float4 v1 = *reinterpret_cast<const float4*>(&red[1 * 1024 + t * 4]);
    const float4 v2 = *reinterpret_cast<const float4*>(&red[2 * 1024 + t * 4]);
    const float4 v3 = *reinterpret_cast<const float4*>(&red[3 * 1024 + t * 4]);
    const float s[4] = {v0.x + v1.x + v2.x + v3.x, v0.y + v1.y + v2.y + v3.y,
                        v0.z + v1.z + v2.z + v3.z, v0.w + v1.w + v2.w + v3.w};
    const int brow = t >> 2;
    const int c4   = (t & 3) * 4;
#pragma unroll
    for (int k = 0; k < 4; ++k)
        atomicAdd(&out[(size_t)brow * O_DIM + o0 + c4 + k], s[k]);

#undef ISSUE
#undef COMMIT
#undef AFLOAD
#undef COMPUTE
}

// ---------------------------------------------------------------------------
extern "C" void kernel_launch(void* const* d_in, const int* in_sizes, int n_in,
                              void* d_out, int out_size, void* d_ws, size_t ws_size,
                              hipStream_t stream) {
    const float* x  = (const float*)d_in[0];
    const float* w1 = (const float*)d_in[1];
    const float* b1 = (const float*)d_in[2];
    const float* w2 = (const float*)d_in[3];
    const float* b2 = (const float*)d_in[4];
    const float* W  = (const float*)d_in[5];
    float* out = (float*)d_out;
    __hip_bfloat16* basis = (__hip_bfloat16*)d_ws;   // 64*16384*2 = 2 MiB

    hipMemsetAsync(d_out, 0, (size_t)out_size * sizeof(float), stream);

    basis_kernel<<<dim3((B_DIM * I_DIM / 8) / 256), dim3(256), 0, stream>>>(
        x, w1, b1, w2, b2, basis);

    dim3 grid(O_DIM / NT, KSPLIT);   // (64, 8) = 512 WGs = 2/CU
    kan_gemm<<<grid, dim3(256), 0, stream>>>(W, basis, out);
}